// Round 6
// baseline (728.811 us; speedup 1.0000x reference)
//
#include <hip/hip_runtime.h>
#include <hip/hip_bf16.h>

#define B_ 256
#define S_ 11
#define D_ 384
#define NHEAD_ 12

typedef const float* bfp;
typedef __attribute__((ext_vector_type(8))) __bf16 bf16x8;
typedef __attribute__((ext_vector_type(4))) float f32x4;

__device__ __forceinline__ bf16x8 ld8_b64(const __bf16* p) {
    union { unsigned long long q[2]; bf16x8 v; } u;
    u.q[0] = *reinterpret_cast<const unsigned long long*>(p);
    u.q[1] = *reinterpret_cast<const unsigned long long*>(p + 4);
    return u.v;
}

// ---------------- MFMA GEMM: C[M,N] = A[M,K] @ W[N,K]^T + bias (+epilogue) ----------------
// Requires M%64==0, N%64==0, K%32==0. mode 0: none, 1: relu, 2: add resid
// aBf16: A is __bf16 (row-major), else float. outBf16: C written as __bf16.
__global__ __launch_bounds__(256) void gemm_mfma_k(
    const void* __restrict__ A_, const float* __restrict__ W,
    const float* __restrict__ bias, const float* __restrict__ resid,
    void* __restrict__ C_, int M, int N, int K, int mode, int aBf16, int outBf16)
{
    __shared__ __align__(16) __bf16 As[64][40];   // +8 pad: 80B row stride
    __shared__ __align__(16) __bf16 Ws[64][40];
    const int tid = threadIdx.x;
    const int bm = blockIdx.y * 64, bn = blockIdx.x * 64;
    const int lane = tid & 63, wv = tid >> 6;
    const int wr = (wv >> 1) * 32, wc = (wv & 1) * 32;
    const int lr = lane & 15, lk = lane >> 4;
    const int arow = tid >> 2, akoff = (tid & 3) * 8;
    f32x4 acc[2][2] = {};
    for (int k0 = 0; k0 < K; k0 += 32) {
        uint4 au;
        float4 a0, a1;
        if (aBf16) {
            const __bf16* ap = (const __bf16*)A_ + (size_t)(bm + arow) * K + k0 + akoff;
            au = *reinterpret_cast<const uint4*>(ap);
        } else {
            const float* ap = (const float*)A_ + (size_t)(bm + arow) * K + k0 + akoff;
            a0 = *reinterpret_cast<const float4*>(ap);
            a1 = *reinterpret_cast<const float4*>(ap + 4);
        }
        const float* wp = W + (size_t)(bn + arow) * K + k0 + akoff;
        float4 w0 = *reinterpret_cast<const float4*>(wp);
        float4 w1 = *reinterpret_cast<const float4*>(wp + 4);
        __syncthreads();  // previous iteration's reads done before overwrite
        if (aBf16) {
            *reinterpret_cast<uint4*>(&As[arow][akoff]) = au;
        } else {
            union { __bf16 h[8]; uint4 u; } pa;
            pa.h[0] = (__bf16)a0.x; pa.h[1] = (__bf16)a0.y; pa.h[2] = (__bf16)a0.z; pa.h[3] = (__bf16)a0.w;
            pa.h[4] = (__bf16)a1.x; pa.h[5] = (__bf16)a1.y; pa.h[6] = (__bf16)a1.z; pa.h[7] = (__bf16)a1.w;
            *reinterpret_cast<uint4*>(&As[arow][akoff]) = pa.u;
        }
        {
            union { __bf16 h[8]; uint4 u; } pw;
            pw.h[0] = (__bf16)w0.x; pw.h[1] = (__bf16)w0.y; pw.h[2] = (__bf16)w0.z; pw.h[3] = (__bf16)w0.w;
            pw.h[4] = (__bf16)w1.x; pw.h[5] = (__bf16)w1.y; pw.h[6] = (__bf16)w1.z; pw.h[7] = (__bf16)w1.w;
            *reinterpret_cast<uint4*>(&Ws[arow][akoff]) = pw.u;
        }
        __syncthreads();
        bf16x8 af0 = *reinterpret_cast<const bf16x8*>(&As[wr + lr][lk * 8]);
        bf16x8 af1 = *reinterpret_cast<const bf16x8*>(&As[wr + 16 + lr][lk * 8]);
        bf16x8 wf0 = *reinterpret_cast<const bf16x8*>(&Ws[wc + lr][lk * 8]);
        bf16x8 wf1 = *reinterpret_cast<const bf16x8*>(&Ws[wc + 16 + lr][lk * 8]);
        acc[0][0] = __builtin_amdgcn_mfma_f32_16x16x32_bf16(af0, wf0, acc[0][0], 0, 0, 0);
        acc[0][1] = __builtin_amdgcn_mfma_f32_16x16x32_bf16(af0, wf1, acc[0][1], 0, 0, 0);
        acc[1][0] = __builtin_amdgcn_mfma_f32_16x16x32_bf16(af1, wf0, acc[1][0], 0, 0, 0);
        acc[1][1] = __builtin_amdgcn_mfma_f32_16x16x32_bf16(af1, wf1, acc[1][1], 0, 0, 0);
    }
    #pragma unroll
    for (int m = 0; m < 2; ++m)
        #pragma unroll
        for (int n = 0; n < 2; ++n) {
            int col = bn + wc + n * 16 + lr;
            float bcol = bias[col];
            #pragma unroll
            for (int i = 0; i < 4; ++i) {
                int row = bm + wr + m * 16 + lk * 4 + i;
                float v = acc[m][n][i] + bcol;
                if (mode == 1) v = fmaxf(v, 0.f);
                if (mode == 2) v += resid[(size_t)row * N + col];
                if (outBf16) ((__bf16*)C_)[(size_t)row * N + col] = (__bf16)v;
                else         ((float*)C_)[(size_t)row * N + col] = v;
            }
        }
}

// ---------------- conv v2: padded-group implicit-im2col MFMA + fused relu/mean ----------------
// k-group g = c*7+ky (21 real, 3 zero-pad), 8 taps each (kx=7 weight=0).
// A-fragment (8 taps of one group) = 8 contiguous cols of a raw LDS input patch.
// Block = (image b, 64-channel half). W staged once; patch staged per 64-position m-tile;
// k-steps are pure LDS reads + MFMA (no barriers).
__global__ __launch_bounds__(256) void convgemm_k(
    bfp __restrict__ img, bfp __restrict__ cw, bfp __restrict__ cb,
    const int* __restrict__ pos0, float* __restrict__ f0pre)
{
    __shared__ __align__(16) __bf16 Wlds[64][200];     // 24 groups x 8 taps, pad to 200
    __shared__ __align__(16) __bf16 P[3][12][136];     // raw patch: 12 rows x 136 cols x 3c
    const int tid = threadIdx.x;
    const int b = blockIdx.x >> 1;
    const int bn = (blockIdx.x & 1) * 64;
    int y = min(max(pos0[0], 0), 127), x = min(max(pos0[1], 0), 127);
    int y1 = max(0, y - 64), y2 = min(128, y + 64);
    int x1 = max(0, x - 64), x2 = min(128, x + 64);
    const int lane = tid & 63, wv = tid >> 6;
    const int wr = (wv >> 1) * 32, wc = (wv & 1) * 32;
    const int lr = lane & 15, lk = lane >> 4;
    const int oyl = wr >> 5;          // which of the 2 output rows in this m-tile
    const int ox0 = lr, ox1 = 16 + lr;

    // stage weights once: 64 rows x 24 groups, 8 taps each (uint4 = 8 bf16)
    for (int e = tid; e < 64 * 24; e += 256) {
        int g = e >> 6, r = e & 63;
        union { __bf16 h[8]; uint4 u; } w;
        #pragma unroll
        for (int kx = 0; kx < 8; ++kx) {
            float v = 0.f;
            if (g < 21 && kx < 7) v = cw[(size_t)(bn + r) * 147 + g * 7 + kx];
            w.h[kx] = (__bf16)v;
        }
        *reinterpret_cast<uint4*>(&Wlds[r][g * 8]) = w.u;
    }

    float s0 = 0.f, s1 = 0.f;
    const float bc0 = cb[bn + wc + lr];
    const float bc1 = cb[bn + wc + 16 + lr];

    for (int mt = 0; mt < 16; ++mt) {
        __syncthreads();  // W ready (mt=0) / prev patch reads done
        // stage raw patch: P flat index == e (c*1632 + r*136 + i)
        for (int e = tid; e < 4896; e += 256) {
            int c = e / 1632, rem = e - c * 1632;
            int r = rem / 136, i = rem - r * 136;
            int rl = mt * 8 - 1 + r, cl = i - 1;
            float v = 0.f;
            if (rl >= 0 && cl >= 0 && (y1 + rl) < y2 && (x1 + cl) < x2)
                v = img[((size_t)(b * 4 + c) * 128 + y1 + rl) * 128 + x1 + cl];
            ((__bf16*)P)[e] = (__bf16)v;
        }
        __syncthreads();
        f32x4 acc[2][2] = {};
        #pragma unroll
        for (int kk = 0; kk < 6; ++kk) {
            int g = kk * 4 + lk;
            int c = g / 7, ky = g - c * 7;
            if (g >= 21) { c = 0; ky = 0; }   // zero-weight groups: any finite data
            const __bf16* prow = &P[c][oyl * 4 + ky][0];
            bf16x8 a0 = ld8_b64(prow + ox0 * 4);
            bf16x8 a1 = ld8_b64(prow + ox1 * 4);
            bf16x8 w0 = *reinterpret_cast<const bf16x8*>(&Wlds[wc + lr][g * 8]);
            bf16x8 w1 = *reinterpret_cast<const bf16x8*>(&Wlds[wc + 16 + lr][g * 8]);
            acc[0][0] = __builtin_amdgcn_mfma_f32_16x16x32_bf16(a0, w0, acc[0][0], 0, 0, 0);
            acc[0][1] = __builtin_amdgcn_mfma_f32_16x16x32_bf16(a0, w1, acc[0][1], 0, 0, 0);
            acc[1][0] = __builtin_amdgcn_mfma_f32_16x16x32_bf16(a1, w0, acc[1][0], 0, 0, 0);
            acc[1][1] = __builtin_amdgcn_mfma_f32_16x16x32_bf16(a1, w1, acc[1][1], 0, 0, 0);
        }
        #pragma unroll
        for (int m = 0; m < 2; ++m)
            #pragma unroll
            for (int i = 0; i < 4; ++i) {
                s0 += fmaxf(acc[m][0][i] + bc0, 0.f);
                s1 += fmaxf(acc[m][1][i] + bc1, 0.f);
            }
    }
    s0 += __shfl_xor(s0, 16); s0 += __shfl_xor(s0, 32);
    s1 += __shfl_xor(s1, 16); s1 += __shfl_xor(s1, 32);
    if (lk == 0) {
        atomicAdd(&f0pre[b * 128 + bn + wc + lr],      s0 * (1.f / 1024.f));
        atomicAdd(&f0pre[b * 128 + bn + wc + 16 + lr], s1 * (1.f / 1024.f));
    }
}

// ---------------- fp32 GEMM (head matmuls — numerics margin) ----------------
#define BM 64
#define BN 64
#define BK 16
__global__ __launch_bounds__(256) void gemm_k(
    const float* __restrict__ A, bfp __restrict__ W,
    bfp __restrict__ bias, const float* __restrict__ resid,
    float* __restrict__ C, int M, int N, int K, int mode)
{
    __shared__ __align__(16) float As[BK][BM + 4];
    __shared__ __align__(16) float Ws[BK][BN + 4];
    const int tx = threadIdx.x & 15, ty = threadIdx.x >> 4;
    const int bm = blockIdx.y * BM, bn = blockIdx.x * BN;
    float acc[4][4] = {};
    for (int k0 = 0; k0 < K; k0 += BK) {
        for (int e = threadIdx.x; e < BM * BK; e += 256) {
            int r = e >> 4, kk = e & 15;
            As[kk][r] = A[(size_t)(bm + r) * K + k0 + kk];
        }
        for (int e = threadIdx.x; e < BN * BK; e += 256) {
            int c = e >> 4, kk = e & 15;
            Ws[kk][c] = W[(size_t)(bn + c) * K + k0 + kk];
        }
        __syncthreads();
        #pragma unroll
        for (int kk = 0; kk < BK; ++kk) {
            float4 av = *reinterpret_cast<const float4*>(&As[kk][ty * 4]);
            float4 wv = *reinterpret_cast<const float4*>(&Ws[kk][tx * 4]);
            float a[4] = {av.x, av.y, av.z, av.w};
            float w[4] = {wv.x, wv.y, wv.z, wv.w};
            #pragma unroll
            for (int i = 0; i < 4; ++i)
                #pragma unroll
                for (int j = 0; j < 4; ++j) acc[i][j] += a[i] * w[j];
        }
        __syncthreads();
    }
    #pragma unroll
    for (int i = 0; i < 4; ++i) {
        int row = bm + ty * 4 + i;
        #pragma unroll
        for (int j = 0; j < 4; ++j) {
            int col = bn + tx * 4 + j;
            float v = acc[i][j] + bias[col];
            if (mode == 1) v = fmaxf(v, 0.f);
            if (mode == 2) v += resid[(size_t)row * N + col];
            C[(size_t)row * N + col] = v;
        }
    }
}

// ---------------- f0 = f0pre @ ext_w^T + ext_b ----------------
__global__ void f0_k(const float* __restrict__ f0pre, bfp __restrict__ ew,
                     bfp __restrict__ eb, float* __restrict__ fbuf0)
{
    int b = blockIdx.x, d = threadIdx.x;
    __shared__ float pre[128];
    if (d < 128) pre[d] = f0pre[b * 128 + d];
    __syncthreads();
    float acc = eb[d];
    for (int co = 0; co < 128; ++co) acc += pre[co] * ew[d * 128 + co];
    fbuf0[b * 384 + d] = acc;
}

// ---------------- win1 gather -> bf16 (B*10, 1728) ----------------
__global__ void win1_k(bfp __restrict__ img, const int* __restrict__ pos1,
                       __bf16* __restrict__ w1)
{
    int i = blockIdx.x * 256 + threadIdx.x;
    if (i >= B_ * 10 * 1728) return;
    int cc = i % 24, r = (i / 24) % 24, c = (i / 576) % 3, s = (i / 1728) % 10, b = i / 17280;
    int y = min(max(pos1[s * 2], 0), 127), x = min(max(pos1[s * 2 + 1], 0), 127);
    int y1 = max(0, y - 12), y2 = min(128, y + 12);
    int x1 = max(0, x - 12), x2 = min(128, x + 12);
    float v = 0.f;
    if ((y1 + r) < y2 && (x1 + cc) < x2)
        v = img[((size_t)(b * 4 + c) * 128 + (y1 + r)) * 128 + (x1 + cc)];
    w1[i] = (__bf16)v;
}

// ---------------- positional features pf[11][384] ----------------
__global__ void pf_k(const int* __restrict__ pos0, const int* __restrict__ pos1,
                     float* __restrict__ pf)
{
    int d = threadIdx.x;
    const float c1 = -logf(10000.f) / 128.f;
    for (int s = 0; s < 11; ++s) {
        int py, px, pw;
        if (s == 0) { py = pos0[0]; px = pos0[1]; pw = 0; }
        else { py = pos1[(s - 1) * 2]; px = pos1[(s - 1) * 2 + 1]; pw = 1; }
        float coordv; int dd = d;
        if (d < 128) coordv = (float)(py - 64);
        else if (d < 256) { coordv = (float)(px - 64); dd = d - 128; }
        else { coordv = (pw == 0) ? 128.f : 24.f; dd = d - 256; }
        int i = dd >> 1;
        float div = expf((float)(2 * i) * c1);
        float ang = coordv * div;
        pf[s * 384 + d] = (dd & 1) ? cosf(ang) : sinf(ang);
    }
}

// ---------------- x = feats + pf ----------------
__global__ void assemble_k(const float* __restrict__ f0, const float* __restrict__ f1,
                           const float* __restrict__ pf, float* __restrict__ x)
{
    int i = blockIdx.x * 256 + threadIdx.x;
    if (i >= B_ * S_ * D_) return;
    int d = i % 384, s = (i / 384) % 11, b = i / (384 * 11);
    float f = (s == 0) ? f0[b * 384 + d] : f1[((size_t)(b * 10) + (s - 1)) * 384 + d];
    x[i] = f + pf[s * 384 + d];
}

// ---------------- attention per (b, head) ----------------
__global__ __launch_bounds__(128) void attn_k(const float* __restrict__ qkv,
                                              float* __restrict__ obuf)
{
    int b = blockIdx.x / NHEAD_, h = blockIdx.x % NHEAD_;
    __shared__ float q[11][32], k[11][32], v[11][32], att[11][12];
    for (int e = threadIdx.x; e < 352; e += 128) {
        int s = e >> 5, d = e & 31;
        size_t base = (size_t)(b * 11 + s) * 1152 + h * 32 + d;
        q[s][d] = qkv[base];
        k[s][d] = qkv[base + 384];
        v[s][d] = qkv[base + 768];
    }
    __syncthreads();
    if (threadIdx.x < 121) {
        int i = threadIdx.x / 11, j = threadIdx.x % 11;
        float s = 0.f;
        #pragma unroll
        for (int d = 0; d < 32; ++d) s += q[i][d] * k[j][d];
        att[i][j] = s * 0.17677669529663687f;
    }
    __syncthreads();
    if (threadIdx.x < 11) {
        int i = threadIdx.x;
        float mx = att[i][0];
        for (int j = 1; j < 11; ++j) mx = fmaxf(mx, att[i][j]);
        float e_[11], sum = 0.f;
        for (int j = 0; j < 11; ++j) { e_[j] = expf(att[i][j] - mx); sum += e_[j]; }
        float inv = 1.f / sum;
        for (int j = 0; j < 11; ++j) att[i][j] = e_[j] * inv;
    }
    __syncthreads();
    for (int e = threadIdx.x; e < 352; e += 128) {
        int i = e >> 5, d = e & 31;
        float s = 0.f;
        #pragma unroll
        for (int j = 0; j < 11; ++j) s += att[i][j] * v[j][d];
        obuf[(size_t)(b * 11 + i) * 384 + h * 32 + d] = s;
    }
}

// ---------------- layernorm rows of [rows,384] ----------------
__global__ __launch_bounds__(128) void ln_k(const float* __restrict__ y, bfp __restrict__ g,
                                            bfp __restrict__ be, float* __restrict__ xo)
{
    int row = blockIdx.x;
    const float* yr = y + (size_t)row * 384;
    int t = threadIdx.x;
    float v0 = yr[t], v1 = yr[t + 128], v2 = yr[t + 256];
    float s = v0 + v1 + v2, sq = v0 * v0 + v1 * v1 + v2 * v2;
    #pragma unroll
    for (int o = 32; o >= 1; o >>= 1) { s += __shfl_xor(s, o); sq += __shfl_xor(sq, o); }
    __shared__ float red[4];
    if ((t & 63) == 0) { red[t >> 6] = s; red[2 + (t >> 6)] = sq; }
    __syncthreads();
    float st = red[0] + red[1], sqt = red[2] + red[3];
    float mean = st * (1.f / 384.f);
    float var = sqt * (1.f / 384.f) - mean * mean;
    float inv = rsqrtf(var + 1e-5f);
    float* xr = xo + (size_t)row * 384;
    xr[t]       = (v0 - mean) * inv * g[t]       + be[t];
    xr[t + 128] = (v1 - mean) * inv * g[t + 128] + be[t + 128];
    xr[t + 256] = (v2 - mean) * inv * g[t + 256] + be[t + 256];
}

// ---------------- m = mean over S ----------------
__global__ void mean_k(const float* __restrict__ x, float* __restrict__ m)
{
    int b = blockIdx.x, d = threadIdx.x;
    float s = 0.f;
    for (int si = 0; si < 11; ++si) s += x[((size_t)b * 11 + si) * 384 + d];
    m[b * 384 + d] = s * (1.f / 11.f);
}

// ---------------- head ----------------
__global__ __launch_bounds__(64) void head_k(const float* __restrict__ h1,
    const float* __restrict__ h2, bfp __restrict__ rw2, bfp __restrict__ rb2,
    bfp __restrict__ uw2, bfp __restrict__ ub2, float* __restrict__ out)
{
    int b = blockIdx.x, lane = threadIdx.x;
    float acc[8] = {};
    for (int d = lane; d < 384; d += 64) {
        float a1 = h1[b * 384 + d], a2 = h2[b * 384 + d];
        #pragma unroll
        for (int o = 0; o < 6; ++o) acc[o] += a1 * rw2[o * 384 + d];
        acc[6] += a2 * uw2[d];
        acc[7] += a2 * uw2[384 + d];
    }
    #pragma unroll
    for (int o = 0; o < 8; ++o)
        #pragma unroll
        for (int off = 32; off >= 1; off >>= 1) acc[o] += __shfl_xor(acc[o], off);
    if (lane == 0) {
        float r[6];
        for (int o = 0; o < 6; ++o) r[o] = acc[o] + rb2[o];
        float u0 = acc[6] + ub2[0], u1 = acc[7] + ub2[1];
        float dot12 = r[0] * r[3] + r[1] * r[4] + r[2] * r[5];
        float q2x = r[3] - dot12 * r[0], q2y = r[4] - dot12 * r[1], q2z = r[5] - dot12 * r[2];
        float q3x = r[1] * q2z - r[2] * q2y;
        float q3y = r[2] * q2x - r[0] * q2z;
        float q3z = r[0] * q2y - r[1] * q2x;
        float n1 = fmaxf(sqrtf(r[0]*r[0] + r[1]*r[1] + r[2]*r[2]), 1e-12f);
        float n2 = fmaxf(sqrtf(q2x*q2x + q2y*q2y + q2z*q2z), 1e-12f);
        float n3 = fmaxf(sqrtf(q3x*q3x + q3y*q3y + q3z*q3z), 1e-12f);
        out[b * 2 + 0] = 1.f / (1.f + expf(-u0));
        out[b * 2 + 1] = 1.f / (1.f + expf(-u1));
        float* R = out + B_ * 2 + b * 9;
        R[0] = r[0] / n1; R[1] = r[1] / n1; R[2] = r[2] / n1;
        R[3] = q2x / n2;  R[4] = q2y / n2;  R[5] = q2z / n2;
        R[6] = q3x / n3;  R[7] = q3y / n3;  R[8] = q3z / n3;
    }
}

extern "C" void kernel_launch(void* const* d_in, const int* in_sizes, int n_in,
                              void* d_out, int out_size, void* d_ws, size_t ws_size,
                              hipStream_t stream)
{
    bfp rgb     = (bfp)d_in[0];
    const int* pos0 = (const int*)d_in[1];
    const int* pos1 = (const int*)d_in[2];
    bfp conv_w  = (bfp)d_in[3];
    bfp conv_b  = (bfp)d_in[4];
    bfp ext_w   = (bfp)d_in[5];
    bfp ext_b   = (bfp)d_in[6];
    bfp proj_w  = (bfp)d_in[7];
    bfp proj_b  = (bfp)d_in[8];
    bfp Wqkv    = (bfp)d_in[9];
    bfp bqkv    = (bfp)d_in[10];
    bfp Wo      = (bfp)d_in[11];
    bfp bo      = (bfp)d_in[12];
    bfp ln1g    = (bfp)d_in[13];
    bfp ln1b    = (bfp)d_in[14];
    bfp ln2g    = (bfp)d_in[15];
    bfp ln2b    = (bfp)d_in[16];
    bfp Wff1    = (bfp)d_in[17];
    bfp bff1    = (bfp)d_in[18];
    bfp Wff2    = (bfp)d_in[19];
    bfp bff2    = (bfp)d_in[20];
    bfp rw1     = (bfp)d_in[21];
    bfp rb1     = (bfp)d_in[22];
    bfp rw2     = (bfp)d_in[23];
    bfp rb2     = (bfp)d_in[24];
    bfp uw1     = (bfp)d_in[25];
    bfp ub1     = (bfp)d_in[26];
    bfp uw2     = (bfp)d_in[27];
    bfp ub2     = (bfp)d_in[28];

    float* ws = (float*)d_ws;
    float* X     = ws;
    float* Y     = ws + 1081344;
    float* QKV   = ws + 2162688;
    float* OBUF  = ws + 5406720;
    float* FFH   = ws + 6488064;       // bf16 region (reused: WIN1F bf16)
    float* PF    = ws + 12255232;
    float* M_    = ws + 12259456;
    float* FBUF1 = QKV;
    float* FBUF0 = QKV + 983040;
    float* F0PRE = QKV + 983040 + 98304;
    __bf16* WIN1F16 = (__bf16*)FFH;
    __bf16* FFH16   = (__bf16*)FFH;
    float* H1    = OBUF;
    float* H2    = OBUF + 98304;

    hipMemsetAsync(F0PRE, 0, 256 * 128 * sizeof(float), stream);

    convgemm_k<<<512, 256, 0, stream>>>(rgb, conv_w, conv_b, pos0, F0PRE);
    win1_k<<<(B_ * 10 * 1728 + 255) / 256, 256, 0, stream>>>(rgb, pos1, WIN1F16);
    f0_k<<<256, 384, 0, stream>>>(F0PRE, ext_w, ext_b, FBUF0);
    gemm_mfma_k<<<dim3(6, 40), 256, 0, stream>>>(WIN1F16, proj_w, proj_b, nullptr,
                                                 FBUF1, 2560, 384, 1728, 0, 1, 0);
    pf_k<<<1, 384, 0, stream>>>(pos0, pos1, PF);
    assemble_k<<<(B_ * S_ * D_ + 255) / 256, 256, 0, stream>>>(FBUF0, FBUF1, PF, X);

    for (int i = 0; i < 4; ++i) {
        gemm_mfma_k<<<dim3(18, 44), 256, 0, stream>>>(
            X, Wqkv + (size_t)i * 1152 * 384, bqkv + i * 1152, nullptr, QKV, 2816, 1152, 384, 0, 0, 0);
        attn_k<<<B_ * NHEAD_, 128, 0, stream>>>(QKV, OBUF);
        gemm_mfma_k<<<dim3(6, 44), 256, 0, stream>>>(
            OBUF, Wo + (size_t)i * 384 * 384, bo + i * 384, X, Y, 2816, 384, 384, 2, 0, 0);
        ln_k<<<2816, 128, 0, stream>>>(Y, ln1g + i * 384, ln1b + i * 384, X);
        gemm_mfma_k<<<dim3(32, 44), 256, 0, stream>>>(
            X, Wff1 + (size_t)i * 2048 * 384, bff1 + i * 2048, nullptr, FFH16, 2816, 2048, 384, 1, 0, 1);
        gemm_mfma_k<<<dim3(6, 44), 256, 0, stream>>>(
            FFH16, Wff2 + (size_t)i * 384 * 2048, bff2 + i * 384, X, Y, 2816, 384, 2048, 2, 1, 0);
        ln_k<<<2816, 128, 0, stream>>>(Y, ln2g + i * 384, ln2b + i * 384, X);
    }

    mean_k<<<256, 384, 0, stream>>>(X, M_);
    gemm_k<<<dim3(384 / BN, 256 / BM), 256, 0, stream>>>(M_, rw1, rb1, nullptr, H1, 256, 384, 384, 1);
    gemm_k<<<dim3(384 / BN, 256 / BM), 256, 0, stream>>>(M_, uw1, ub1, nullptr, H2, 256, 384, 384, 1);
    head_k<<<256, 64, 0, stream>>>(H1, H2, rw2, rb2, uw2, ub2, (float*)d_out);
}

// Round 7
// 555.922 us; speedup vs baseline: 1.3110x; 1.3110x over previous
//
#include <hip/hip_runtime.h>
#include <hip/hip_bf16.h>

#define B_ 256
#define S_ 11
#define D_ 384
#define NHEAD_ 12

typedef const float* bfp;
typedef __attribute__((ext_vector_type(8))) __bf16 bf16x8;
typedef __attribute__((ext_vector_type(4))) float f32x4;

__device__ __forceinline__ bf16x8 ld8_b64(const __bf16* p) {
    union { unsigned long long q[2]; bf16x8 v; } u;
    u.q[0] = *reinterpret_cast<const unsigned long long*>(p);
    u.q[1] = *reinterpret_cast<const unsigned long long*>(p + 4);
    return u.v;
}

// ---------------- fp32 -> bf16 bulk convert (weights, once per launch) ----------------
__global__ void f2b_k(const float* __restrict__ s, __bf16* __restrict__ d, int n4)
{
    int i = blockIdx.x * 256 + threadIdx.x;
    if (i >= n4) return;
    float4 v = reinterpret_cast<const float4*>(s)[i];
    union { __bf16 h[4]; unsigned long long u; } p;
    p.h[0] = (__bf16)v.x; p.h[1] = (__bf16)v.y;
    p.h[2] = (__bf16)v.z; p.h[3] = (__bf16)v.w;
    reinterpret_cast<unsigned long long*>(d)[i] = p.u;
}

// ---------------- conv weight pad: [128][147] -> bf16 [128][24*8] (tap7 = 0) ----------------
__global__ void prep_wpad_k(bfp __restrict__ cw, __bf16* __restrict__ wpad)
{
    int e = blockIdx.x * 256 + threadIdx.x;   // 128*24
    if (e >= 3072) return;
    int r = e >> 5, g = e & 31;               // 32 > 24: guard
    if (g >= 24) return;
    union { __bf16 h[8]; uint4 u; } w;
    #pragma unroll
    for (int kx = 0; kx < 8; ++kx) {
        float v = 0.f;
        if (g < 21 && kx < 7) v = cw[(size_t)r * 147 + g * 7 + kx];
        w.h[kx] = (__bf16)v;
    }
    *reinterpret_cast<uint4*>(&wpad[(size_t)r * 192 + g * 8]) = w.u;
}

// ---------------- all-bf16 MFMA GEMM, BK=64: C[M,N] = A[M,K] @ W[N,K]^T + bias ----------------
// mode 0: none, 1: relu, 2: add resid (fp32). outBf16: C as bf16 else fp32.
__global__ __launch_bounds__(256) void gemm_bb_k(
    const __bf16* __restrict__ A, const __bf16* __restrict__ W,
    const float* __restrict__ bias, const float* __restrict__ resid,
    void* __restrict__ C_, int M, int N, int K, int mode, int outBf16)
{
    __shared__ __align__(16) __bf16 As[64][72];   // +8 pad: 144B row stride
    __shared__ __align__(16) __bf16 Ws[64][72];
    const int tid = threadIdx.x;
    const int bm = blockIdx.y * 64, bn = blockIdx.x * 64;
    const int lane = tid & 63, wv = tid >> 6;
    const int wr = (wv >> 1) * 32, wc = (wv & 1) * 32;
    const int lr = lane & 15, lk = lane >> 4;
    const int arow = tid >> 2, koff = (tid & 3) * 16;
    f32x4 acc[2][2] = {};
    for (int k0 = 0; k0 < K; k0 += 64) {
        const __bf16* ap = A + (size_t)(bm + arow) * K + k0 + koff;
        uint4 qa0 = *reinterpret_cast<const uint4*>(ap);
        uint4 qa1 = *reinterpret_cast<const uint4*>(ap + 8);
        const __bf16* wp = W + (size_t)(bn + arow) * K + k0 + koff;
        uint4 qw0 = *reinterpret_cast<const uint4*>(wp);
        uint4 qw1 = *reinterpret_cast<const uint4*>(wp + 8);
        __syncthreads();
        *reinterpret_cast<uint4*>(&As[arow][koff])     = qa0;
        *reinterpret_cast<uint4*>(&As[arow][koff + 8]) = qa1;
        *reinterpret_cast<uint4*>(&Ws[arow][koff])     = qw0;
        *reinterpret_cast<uint4*>(&Ws[arow][koff + 8]) = qw1;
        __syncthreads();
        #pragma unroll
        for (int s = 0; s < 2; ++s) {
            bf16x8 a0 = *reinterpret_cast<const bf16x8*>(&As[wr + lr][s * 32 + lk * 8]);
            bf16x8 a1 = *reinterpret_cast<const bf16x8*>(&As[wr + 16 + lr][s * 32 + lk * 8]);
            bf16x8 w0 = *reinterpret_cast<const bf16x8*>(&Ws[wc + lr][s * 32 + lk * 8]);
            bf16x8 w1 = *reinterpret_cast<const bf16x8*>(&Ws[wc + 16 + lr][s * 32 + lk * 8]);
            acc[0][0] = __builtin_amdgcn_mfma_f32_16x16x32_bf16(a0, w0, acc[0][0], 0, 0, 0);
            acc[0][1] = __builtin_amdgcn_mfma_f32_16x16x32_bf16(a0, w1, acc[0][1], 0, 0, 0);
            acc[1][0] = __builtin_amdgcn_mfma_f32_16x16x32_bf16(a1, w0, acc[1][0], 0, 0, 0);
            acc[1][1] = __builtin_amdgcn_mfma_f32_16x16x32_bf16(a1, w1, acc[1][1], 0, 0, 0);
        }
    }
    #pragma unroll
    for (int m = 0; m < 2; ++m)
        #pragma unroll
        for (int n = 0; n < 2; ++n) {
            int col = bn + wc + n * 16 + lr;
            float bcol = bias[col];
            #pragma unroll
            for (int i = 0; i < 4; ++i) {
                int row = bm + wr + m * 16 + lk * 4 + i;
                float v = acc[m][n][i] + bcol;
                if (mode == 1) v = fmaxf(v, 0.f);
                if (mode == 2) v += resid[(size_t)row * N + col];
                if (outBf16) ((__bf16*)C_)[(size_t)row * N + col] = (__bf16)v;
                else         ((float*)C_)[(size_t)row * N + col] = v;
            }
        }
}

// ---------------- conv v3: padded-group implicit-im2col MFMA, 2048 blocks ----------------
__global__ __launch_bounds__(256) void convgemm_k(
    bfp __restrict__ img, const __bf16* __restrict__ wpad, bfp __restrict__ cb,
    const int* __restrict__ pos0, float* __restrict__ f0pre)
{
    __shared__ __align__(16) __bf16 Wlds[64][200];   // 400B row stride (2-way banks)
    __shared__ __align__(16) __bf16 P[3][12][136];
    const int tid = threadIdx.x;
    const int blk = blockIdx.x;           // (b:256) x (half:2) x (mtg:4)
    const int b = blk >> 3;
    const int bn = ((blk >> 2) & 1) * 64;
    const int mtg = blk & 3;
    int y = min(max(pos0[0], 0), 127), x = min(max(pos0[1], 0), 127);
    int y1 = max(0, y - 64), y2 = min(128, y + 64);
    int x1 = max(0, x - 64), x2 = min(128, x + 64);
    const int lane = tid & 63, wv = tid >> 6;
    const int wr = (wv >> 1) * 32, wc = (wv & 1) * 32;
    const int lr = lane & 15, lk = lane >> 4;
    const int oyl = wr >> 5;
    const int ox0 = lr, ox1 = 16 + lr;

    // stage weights: pure uint4 copies from pre-padded global
    for (int e = tid; e < 1536; e += 256) {
        int r = e / 24, g = e - r * 24;
        uint4 q = *reinterpret_cast<const uint4*>(&wpad[(size_t)(bn + r) * 192 + g * 8]);
        *reinterpret_cast<uint4*>(&Wlds[r][g * 8]) = q;
    }

    float s0 = 0.f, s1 = 0.f;
    const float bc0 = cb[bn + wc + lr];
    const float bc1 = cb[bn + wc + 16 + lr];

    for (int t = 0; t < 4; ++t) {
        int mt = mtg * 4 + t;
        __syncthreads();   // W ready (t=0) / prev patch reads done
        // stage raw patch, 2 elems per thread-op
        for (int e = tid; e < 2448; e += 256) {
            int c = e / 816, rem = e - c * 816;
            int r2 = rem / 68, ip2 = (rem - r2 * 68) * 2;
            int rl = mt * 8 - 1 + r2;
            bool rok = (rl >= 0) && ((y1 + rl) < y2);
            const float* row = img + ((size_t)(b * 4 + c) * 128 + y1 + rl) * 128 + x1;
            int cl0 = ip2 - 1, cl1 = ip2;
            float v0 = 0.f, v1 = 0.f;
            if (rok && cl0 >= 0 && (x1 + cl0) < x2) v0 = row[cl0];
            if (rok && (x1 + cl1) < x2)             v1 = row[cl1];
            union { __bf16 h[2]; unsigned int u; } p;
            p.h[0] = (__bf16)v0; p.h[1] = (__bf16)v1;
            *reinterpret_cast<unsigned int*>(&P[c][r2][ip2]) = p.u;
        }
        __syncthreads();
        f32x4 acc[2][2] = {};
        #pragma unroll
        for (int kk = 0; kk < 6; ++kk) {
            int g = kk * 4 + lk;
            int c = g / 7, ky = g - c * 7;
            if (g >= 21) { c = 0; ky = 0; }   // zero-weight pad groups
            const __bf16* prow = &P[c][oyl * 4 + ky][0];
            bf16x8 a0 = ld8_b64(prow + ox0 * 4);
            bf16x8 a1 = ld8_b64(prow + ox1 * 4);
            bf16x8 w0 = *reinterpret_cast<const bf16x8*>(&Wlds[wc + lr][g * 8]);
            bf16x8 w1 = *reinterpret_cast<const bf16x8*>(&Wlds[wc + 16 + lr][g * 8]);
            acc[0][0] = __builtin_amdgcn_mfma_f32_16x16x32_bf16(a0, w0, acc[0][0], 0, 0, 0);
            acc[0][1] = __builtin_amdgcn_mfma_f32_16x16x32_bf16(a0, w1, acc[0][1], 0, 0, 0);
            acc[1][0] = __builtin_amdgcn_mfma_f32_16x16x32_bf16(a1, w0, acc[1][0], 0, 0, 0);
            acc[1][1] = __builtin_amdgcn_mfma_f32_16x16x32_bf16(a1, w1, acc[1][1], 0, 0, 0);
        }
        #pragma unroll
        for (int m = 0; m < 2; ++m)
            #pragma unroll
            for (int i = 0; i < 4; ++i) {
                s0 += fmaxf(acc[m][0][i] + bc0, 0.f);
                s1 += fmaxf(acc[m][1][i] + bc1, 0.f);
            }
    }
    s0 += __shfl_xor(s0, 16); s0 += __shfl_xor(s0, 32);
    s1 += __shfl_xor(s1, 16); s1 += __shfl_xor(s1, 32);
    if (lk == 0) {
        atomicAdd(&f0pre[b * 128 + bn + wc + lr],      s0 * (1.f / 1024.f));
        atomicAdd(&f0pre[b * 128 + bn + wc + 16 + lr], s1 * (1.f / 1024.f));
    }
}

// ---------------- fp32 GEMM (head matmuls — numerics margin) ----------------
#define BM 64
#define BN 64
#define BK 16
__global__ __launch_bounds__(256) void gemm_k(
    const float* __restrict__ A, bfp __restrict__ W,
    bfp __restrict__ bias, const float* __restrict__ resid,
    float* __restrict__ C, int M, int N, int K, int mode)
{
    __shared__ __align__(16) float As[BK][BM + 4];
    __shared__ __align__(16) float Ws[BK][BN + 4];
    const int tx = threadIdx.x & 15, ty = threadIdx.x >> 4;
    const int bm = blockIdx.y * BM, bn = blockIdx.x * BN;
    float acc[4][4] = {};
    for (int k0 = 0; k0 < K; k0 += BK) {
        for (int e = threadIdx.x; e < BM * BK; e += 256) {
            int r = e >> 4, kk = e & 15;
            As[kk][r] = A[(size_t)(bm + r) * K + k0 + kk];
        }
        for (int e = threadIdx.x; e < BN * BK; e += 256) {
            int c = e >> 4, kk = e & 15;
            Ws[kk][c] = W[(size_t)(bn + c) * K + k0 + kk];
        }
        __syncthreads();
        #pragma unroll
        for (int kk = 0; kk < BK; ++kk) {
            float4 av = *reinterpret_cast<const float4*>(&As[kk][ty * 4]);
            float4 wv = *reinterpret_cast<const float4*>(&Ws[kk][tx * 4]);
            float a[4] = {av.x, av.y, av.z, av.w};
            float w[4] = {wv.x, wv.y, wv.z, wv.w};
            #pragma unroll
            for (int i = 0; i < 4; ++i)
                #pragma unroll
                for (int j = 0; j < 4; ++j) acc[i][j] += a[i] * w[j];
        }
        __syncthreads();
    }
    #pragma unroll
    for (int i = 0; i < 4; ++i) {
        int row = bm + ty * 4 + i;
        #pragma unroll
        for (int j = 0; j < 4; ++j) {
            int col = bn + tx * 4 + j;
            float v = acc[i][j] + bias[col];
            if (mode == 1) v = fmaxf(v, 0.f);
            if (mode == 2) v += resid[(size_t)row * N + col];
            C[(size_t)row * N + col] = v;
        }
    }
}

// ---------------- f0 = f0pre @ ext_w^T + ext_b ----------------
__global__ void f0_k(const float* __restrict__ f0pre, bfp __restrict__ ew,
                     bfp __restrict__ eb, float* __restrict__ fbuf0)
{
    int b = blockIdx.x, d = threadIdx.x;
    __shared__ float pre[128];
    if (d < 128) pre[d] = f0pre[b * 128 + d];
    __syncthreads();
    float acc = eb[d];
    for (int co = 0; co < 128; ++co) acc += pre[co] * ew[d * 128 + co];
    fbuf0[b * 384 + d] = acc;
}

// ---------------- win1 gather -> bf16 (B*10, 1728) ----------------
__global__ void win1_k(bfp __restrict__ img, const int* __restrict__ pos1,
                       __bf16* __restrict__ w1)
{
    int i = blockIdx.x * 256 + threadIdx.x;
    if (i >= B_ * 10 * 1728) return;
    int cc = i % 24, r = (i / 24) % 24, c = (i / 576) % 3, s = (i / 1728) % 10, b = i / 17280;
    int y = min(max(pos1[s * 2], 0), 127), x = min(max(pos1[s * 2 + 1], 0), 127);
    int y1 = max(0, y - 12), y2 = min(128, y + 12);
    int x1 = max(0, x - 12), x2 = min(128, x + 12);
    float v = 0.f;
    if ((y1 + r) < y2 && (x1 + cc) < x2)
        v = img[((size_t)(b * 4 + c) * 128 + (y1 + r)) * 128 + (x1 + cc)];
    w1[i] = (__bf16)v;
}

// ---------------- positional features pf[11][384] ----------------
__global__ void pf_k(const int* __restrict__ pos0, const int* __restrict__ pos1,
                     float* __restrict__ pf)
{
    int d = threadIdx.x;
    const float c1 = -logf(10000.f) / 128.f;
    for (int s = 0; s < 11; ++s) {
        int py, px, pw;
        if (s == 0) { py = pos0[0]; px = pos0[1]; pw = 0; }
        else { py = pos1[(s - 1) * 2]; px = pos1[(s - 1) * 2 + 1]; pw = 1; }
        float coordv; int dd = d;
        if (d < 128) coordv = (float)(py - 64);
        else if (d < 256) { coordv = (float)(px - 64); dd = d - 128; }
        else { coordv = (pw == 0) ? 128.f : 24.f; dd = d - 256; }
        int i = dd >> 1;
        float div = expf((float)(2 * i) * c1);
        float ang = coordv * div;
        pf[s * 384 + d] = (dd & 1) ? cosf(ang) : sinf(ang);
    }
}

// ---------------- x = feats + pf (fp32 + bf16) ----------------
__global__ void assemble_k(const float* __restrict__ f0, const float* __restrict__ f1,
                           const float* __restrict__ pf, float* __restrict__ x,
                           __bf16* __restrict__ xb)
{
    int i = blockIdx.x * 256 + threadIdx.x;
    if (i >= B_ * S_ * D_) return;
    int d = i % 384, s = (i / 384) % 11, b = i / (384 * 11);
    float f = (s == 0) ? f0[b * 384 + d] : f1[((size_t)(b * 10) + (s - 1)) * 384 + d];
    float v = f + pf[s * 384 + d];
    x[i] = v;
    xb[i] = (__bf16)v;
}

// ---------------- attention per (b, head); out bf16 ----------------
__global__ __launch_bounds__(128) void attn_k(const float* __restrict__ qkv,
                                              __bf16* __restrict__ obuf)
{
    int b = blockIdx.x / NHEAD_, h = blockIdx.x % NHEAD_;
    __shared__ float q[11][32], k[11][32], v[11][32], att[11][12];
    for (int e = threadIdx.x; e < 352; e += 128) {
        int s = e >> 5, d = e & 31;
        size_t base = (size_t)(b * 11 + s) * 1152 + h * 32 + d;
        q[s][d] = qkv[base];
        k[s][d] = qkv[base + 384];
        v[s][d] = qkv[base + 768];
    }
    __syncthreads();
    if (threadIdx.x < 121) {
        int i = threadIdx.x / 11, j = threadIdx.x % 11;
        float s = 0.f;
        #pragma unroll
        for (int d = 0; d < 32; ++d) s += q[i][d] * k[j][d];
        att[i][j] = s * 0.17677669529663687f;
    }
    __syncthreads();
    if (threadIdx.x < 11) {
        int i = threadIdx.x;
        float mx = att[i][0];
        for (int j = 1; j < 11; ++j) mx = fmaxf(mx, att[i][j]);
        float e_[11], sum = 0.f;
        for (int j = 0; j < 11; ++j) { e_[j] = expf(att[i][j] - mx); sum += e_[j]; }
        float inv = 1.f / sum;
        for (int j = 0; j < 11; ++j) att[i][j] = e_[j] * inv;
    }
    __syncthreads();
    for (int e = threadIdx.x; e < 352; e += 128) {
        int i = e >> 5, d = e & 31;
        float s = 0.f;
        #pragma unroll
        for (int j = 0; j < 11; ++j) s += att[i][j] * v[j][d];
        obuf[(size_t)(b * 11 + i) * 384 + h * 32 + d] = (__bf16)s;
    }
}

// ---------------- layernorm rows of [rows,384] -> fp32 + bf16 ----------------
__global__ __launch_bounds__(128) void ln_k(const float* __restrict__ y, bfp __restrict__ g,
                                            bfp __restrict__ be, float* __restrict__ xo,
                                            __bf16* __restrict__ xb)
{
    int row = blockIdx.x;
    const float* yr = y + (size_t)row * 384;
    int t = threadIdx.x;
    float v0 = yr[t], v1 = yr[t + 128], v2 = yr[t + 256];
    float s = v0 + v1 + v2, sq = v0 * v0 + v1 * v1 + v2 * v2;
    #pragma unroll
    for (int o = 32; o >= 1; o >>= 1) { s += __shfl_xor(s, o); sq += __shfl_xor(sq, o); }
    __shared__ float red[4];
    if ((t & 63) == 0) { red[t >> 6] = s; red[2 + (t >> 6)] = sq; }
    __syncthreads();
    float st = red[0] + red[1], sqt = red[2] + red[3];
    float mean = st * (1.f / 384.f);
    float var = sqt * (1.f / 384.f) - mean * mean;
    float inv = rsqrtf(var + 1e-5f);
    float* xr = xo + (size_t)row * 384;
    __bf16* xbr = xb + (size_t)row * 384;
    float o0 = (v0 - mean) * inv * g[t]       + be[t];
    float o1 = (v1 - mean) * inv * g[t + 128] + be[t + 128];
    float o2 = (v2 - mean) * inv * g[t + 256] + be[t + 256];
    xr[t] = o0; xr[t + 128] = o1; xr[t + 256] = o2;
    xbr[t] = (__bf16)o0; xbr[t + 128] = (__bf16)o1; xbr[t + 256] = (__bf16)o2;
}

// ---------------- m = mean over S ----------------
__global__ void mean_k(const float* __restrict__ x, float* __restrict__ m)
{
    int b = blockIdx.x, d = threadIdx.x;
    float s = 0.f;
    for (int si = 0; si < 11; ++si) s += x[((size_t)b * 11 + si) * 384 + d];
    m[b * 384 + d] = s * (1.f / 11.f);
}

// ---------------- head ----------------
__global__ __launch_bounds__(64) void head_k(const float* __restrict__ h1,
    const float* __restrict__ h2, bfp __restrict__ rw2, bfp __restrict__ rb2,
    bfp __restrict__ uw2, bfp __restrict__ ub2, float* __restrict__ out)
{
    int b = blockIdx.x, lane = threadIdx.x;
    float acc[8] = {};
    for (int d = lane; d < 384; d += 64) {
        float a1 = h1[b * 384 + d], a2 = h2[b * 384 + d];
        #pragma unroll
        for (int o = 0; o < 6; ++o) acc[o] += a1 * rw2[o * 384 + d];
        acc[6] += a2 * uw2[d];
        acc[7] += a2 * uw2[384 + d];
    }
    #pragma unroll
    for (int o = 0; o < 8; ++o)
        #pragma unroll
        for (int off = 32; off >= 1; off >>= 1) acc[o] += __shfl_xor(acc[o], off);
    if (lane == 0) {
        float r[6];
        for (int o = 0; o < 6; ++o) r[o] = acc[o] + rb2[o];
        float u0 = acc[6] + ub2[0], u1 = acc[7] + ub2[1];
        float dot12 = r[0] * r[3] + r[1] * r[4] + r[2] * r[5];
        float q2x = r[3] - dot12 * r[0], q2y = r[4] - dot12 * r[1], q2z = r[5] - dot12 * r[2];
        float q3x = r[1] * q2z - r[2] * q2y;
        float q3y = r[2] * q2x - r[0] * q2z;
        float q3z = r[0] * q2y - r[1] * q2x;
        float n1 = fmaxf(sqrtf(r[0]*r[0] + r[1]*r[1] + r[2]*r[2]), 1e-12f);
        float n2 = fmaxf(sqrtf(q2x*q2x + q2y*q2y + q2z*q2z), 1e-12f);
        float n3 = fmaxf(sqrtf(q3x*q3x + q3y*q3y + q3z*q3z), 1e-12f);
        out[b * 2 + 0] = 1.f / (1.f + expf(-u0));
        out[b * 2 + 1] = 1.f / (1.f + expf(-u1));
        float* R = out + B_ * 2 + b * 9;
        R[0] = r[0] / n1; R[1] = r[1] / n1; R[2] = r[2] / n1;
        R[3] = q2x / n2;  R[4] = q2y / n2;  R[5] = q2z / n2;
        R[6] = q3x / n3;  R[7] = q3y / n3;  R[8] = q3z / n3;
    }
}

extern "C" void kernel_launch(void* const* d_in, const int* in_sizes, int n_in,
                              void* d_out, int out_size, void* d_ws, size_t ws_size,
                              hipStream_t stream)
{
    bfp rgb     = (bfp)d_in[0];
    const int* pos0 = (const int*)d_in[1];
    const int* pos1 = (const int*)d_in[2];
    bfp conv_w  = (bfp)d_in[3];
    bfp conv_b  = (bfp)d_in[4];
    bfp ext_w   = (bfp)d_in[5];
    bfp ext_b   = (bfp)d_in[6];
    bfp proj_w  = (bfp)d_in[7];
    bfp proj_b  = (bfp)d_in[8];
    bfp Wqkv    = (bfp)d_in[9];
    bfp bqkv    = (bfp)d_in[10];
    bfp Wo      = (bfp)d_in[11];
    bfp bo      = (bfp)d_in[12];
    bfp ln1g    = (bfp)d_in[13];
    bfp ln1b    = (bfp)d_in[14];
    bfp ln2g    = (bfp)d_in[15];
    bfp ln2b    = (bfp)d_in[16];
    bfp Wff1    = (bfp)d_in[17];
    bfp bff1    = (bfp)d_in[18];
    bfp Wff2    = (bfp)d_in[19];
    bfp bff2    = (bfp)d_in[20];
    bfp rw1     = (bfp)d_in[21];
    bfp rb1     = (bfp)d_in[22];
    bfp rw2     = (bfp)d_in[23];
    bfp rb2     = (bfp)d_in[24];
    bfp uw1     = (bfp)d_in[25];
    bfp ub1     = (bfp)d_in[26];
    bfp uw2     = (bfp)d_in[27];
    bfp ub2     = (bfp)d_in[28];

    float* ws = (float*)d_ws;
    float*  X      = ws;                         // 1,081,344 f
    float*  Y      = ws + 1081344;               // 1,081,344 f
    float*  QKV    = ws + 2162688;               // 3,244,032 f (reuse: FBUF1/FBUF0/F0PRE)
    float*  FBUF1  = QKV;
    float*  FBUF0  = QKV + 983040;
    float*  F0PRE  = QKV + 983040 + 98304;
    __bf16* OBUFb  = (__bf16*)(ws + 5406720);    // 1,081,344 e = 540,672 f
    float*  H1     = ws + 5947392;               // 98,304 f
    float*  H2     = ws + 6045696;               // 98,304 f
    __bf16* FFH16  = (__bf16*)(ws + 6144000);    // 5,767,168 e = 2,883,584 f (reuse: WIN1F16)
    __bf16* WIN1F16= FFH16;
    float*  PF     = ws + 9027584;               // 4,224 f
    float*  M_     = ws + 9031808;               // 98,304 f
    __bf16* Xb     = (__bf16*)(ws + 9130112);    // 1,081,344 e = 540,672 f
    __bf16* projWb = (__bf16*)(ws + 9670784);    // 663,552 e
    __bf16* WqkvB  = (__bf16*)(ws + 10002560);   // 1,769,472 e
    __bf16* WoB    = (__bf16*)(ws + 10887296);   // 589,824 e
    __bf16* Wff1B  = (__bf16*)(ws + 11182208);   // 3,145,728 e
    __bf16* Wff2B  = (__bf16*)(ws + 12755072);   // 3,145,728 e
    __bf16* WpadC  = (__bf16*)(ws + 14327936);   // 24,576 e

    hipMemsetAsync(F0PRE, 0, 256 * 128 * sizeof(float), stream);

    // one-time weight conversions
    f2b_k<<<648,  256, 0, stream>>>(proj_w, projWb, 165888);
    f2b_k<<<1728, 256, 0, stream>>>(Wqkv,   WqkvB,  442368);
    f2b_k<<<576,  256, 0, stream>>>(Wo,     WoB,    147456);
    f2b_k<<<3072, 256, 0, stream>>>(Wff1,   Wff1B,  786432);
    f2b_k<<<3072, 256, 0, stream>>>(Wff2,   Wff2B,  786432);
    prep_wpad_k<<<16, 256, 0, stream>>>(conv_w, WpadC);

    convgemm_k<<<2048, 256, 0, stream>>>(rgb, WpadC, conv_b, pos0, F0PRE);
    win1_k<<<(B_ * 10 * 1728 + 255) / 256, 256, 0, stream>>>(rgb, pos1, WIN1F16);
    f0_k<<<256, 384, 0, stream>>>(F0PRE, ext_w, ext_b, FBUF0);
    gemm_bb_k<<<dim3(6, 40), 256, 0, stream>>>(WIN1F16, projWb, proj_b, nullptr,
                                               FBUF1, 2560, 384, 1728, 0, 0);
    pf_k<<<1, 384, 0, stream>>>(pos0, pos1, PF);
    assemble_k<<<(B_ * S_ * D_ + 255) / 256, 256, 0, stream>>>(FBUF0, FBUF1, PF, X, Xb);

    for (int i = 0; i < 4; ++i) {
        gemm_bb_k<<<dim3(18, 44), 256, 0, stream>>>(
            Xb, WqkvB + (size_t)i * 1152 * 384, bqkv + i * 1152, nullptr, QKV, 2816, 1152, 384, 0, 0);
        attn_k<<<B_ * NHEAD_, 128, 0, stream>>>(QKV, OBUFb);
        gemm_bb_k<<<dim3(6, 44), 256, 0, stream>>>(
            OBUFb, WoB + (size_t)i * 384 * 384, bo + i * 384, X, Y, 2816, 384, 384, 2, 0);
        ln_k<<<2816, 128, 0, stream>>>(Y, ln1g + i * 384, ln1b + i * 384, X, Xb);
        gemm_bb_k<<<dim3(32, 44), 256, 0, stream>>>(
            Xb, Wff1B + (size_t)i * 2048 * 384, bff1 + i * 2048, nullptr, FFH16, 2816, 2048, 384, 1, 1);
        gemm_bb_k<<<dim3(6, 44), 256, 0, stream>>>(
            FFH16, Wff2B + (size_t)i * 384 * 2048, bff2 + i * 384, X, Y, 2816, 384, 2048, 2, 0);
        ln_k<<<2816, 128, 0, stream>>>(Y, ln2g + i * 384, ln2b + i * 384, X, Xb);
    }

    mean_k<<<256, 384, 0, stream>>>(X, M_);
    gemm_k<<<dim3(384 / BN, 256 / BM), 256, 0, stream>>>(M_, rw1, rb1, nullptr, H1, 256, 384, 384, 1);
    gemm_k<<<dim3(384 / BN, 256 / BM), 256, 0, stream>>>(M_, uw1, ub1, nullptr, H2, 256, 384, 384, 1);
    head_k<<<256, 64, 0, stream>>>(H1, H2, rw2, rb2, uw2, ub2, (float*)d_out);
}